// Round 6
// baseline (452.072 us; speedup 1.0000x reference)
//
#include <hip/hip_runtime.h>
#include <math.h>

#define NFILT 64
#define FRAME_STEP 160
#define NQ 7               // 7 float4 = 28 weight slots/lane (window<=24 + align<=3)
#define WAVES 4
#define NBLOCKS 1536
#define PWPAD 284          // 257 bins + 27 pad so the aligned float4 window can overrun

// ---------------- cross-lane primitives (documented patterns only) ----------------
template<int CTRL>
__device__ __forceinline__ float xdpp(float v) {   // DPP lane shuffle (VALU pipe)
    return __int_as_float(__builtin_amdgcn_update_dpp(
        0, __float_as_int(v), CTRL, 0xF, 0xF, true));
}
template<int OFF>
__device__ __forceinline__ float swzx(float v) {   // ds_swizzle BitMode (1 DS op)
    return __int_as_float(__builtin_amdgcn_ds_swizzle(__float_as_int(v), OFF));
}
// full-wave sum broadcast to all lanes, two independent chains interleaved:
// xor1,xor2 (quad_perm) -> ror4+ror8 (row sums; ror:8==xor8, ror:4 after quad
// sums is order-insensitive for +) -> xor16 (swizzle) -> xor32 (bpermute)
__device__ __forceinline__ void sum64x2(float &u, float &w) {
    u += xdpp<0xB1>(u);   w += xdpp<0xB1>(w);    // quad_perm [1,0,3,2] = xor 1
    u += xdpp<0x4E>(u);   w += xdpp<0x4E>(w);    // quad_perm [2,3,0,1] = xor 2
    u += xdpp<0x124>(u);  w += xdpp<0x124>(w);   // row_ror:4
    u += xdpp<0x128>(u);  w += xdpp<0x128>(w);   // row_ror:8  -> row(16) sums
    u += swzx<0x401F>(u); w += swzx<0x401F>(w);  // xor 16     -> 32-half sums
    u += __shfl_xor(u, 32, 64);
    w += __shfl_xor(w, 32, 64);                  // cross-half -> full-wave total
}

// ---- load one 400-sample frame (8/lane, lanes 0..49) + pre-emphasis ----
__device__ __forceinline__ void load_pre(const float* __restrict__ x, long base,
                                         int l, bool valid, float (&v)[8]) {
    float a0=0,a1=0,a2=0,a3=0,a4=0,a5=0,a6=0,a7=0;
    if (valid && l < 50) {
        const float4* p4 = reinterpret_cast<const float4*>(x + base + 8 * l);
        float4 A = p4[0], B = p4[1];
        a0=A.x; a1=A.y; a2=A.z; a3=A.w; a4=B.x; a5=B.y; a6=B.z; a7=B.w;
    }
    float edge = 0.0f;
    if (valid && base > 0) edge = x[base - 1];   // pre[0] of audio = x[0] - 0.97*0
    float prev = __shfl_up(a7, 1, 64);
    if (l == 0) prev = edge;
    const bool act = valid && (l < 50);
    v[0] = act ? fmaf(-0.97f, prev, a0) : 0.0f;
    v[1] = act ? fmaf(-0.97f, a0, a1) : 0.0f;
    v[2] = act ? fmaf(-0.97f, a1, a2) : 0.0f;
    v[3] = act ? fmaf(-0.97f, a2, a3) : 0.0f;
    v[4] = act ? fmaf(-0.97f, a3, a4) : 0.0f;
    v[5] = act ? fmaf(-0.97f, a4, a5) : 0.0f;
    v[6] = act ? fmaf(-0.97f, a5, a6) : 0.0f;
    v[7] = act ? fmaf(-0.97f, a6, a7) : 0.0f;
}

// ---- 512-pt FFT: 64-pt cross-lane stage mix (1 bpermute + 3 swizzle + 2 DPP)
//      + W512 twiddle + in-register radix-8.  Math identical to the R3-verified
//      version; only the shuffle transport differs per stage. ----
__device__ __forceinline__ void fft512(float (&vr)[8], float (&vi)[8],
                                       const float (&cA)[6], const float (&sA)[6],
                                       const float (&sg)[6],
                                       const float (&br)[8], const float (&bi)[8]) {
    // j=0, d=32: ds_bpermute (only stage crossing the 32-lane halves)
    {
        const float c = cA[0], s = sA[0], g = sg[0];
#pragma unroll
        for (int r = 0; r < 8; r++) {
            float pr = __shfl_xor(vr[r], 32, 64);
            float pi = __shfl_xor(vi[r], 32, 64);
            float tr = fmaf(g, vr[r], pr), ti = fmaf(g, vi[r], pi);
            vr[r] = tr * c - ti * s;
            vi[r] = tr * s + ti * c;
        }
    }
    // j=1, d=16: ds_swizzle xor-16
    {
        const float c = cA[1], s = sA[1], g = sg[1];
#pragma unroll
        for (int r = 0; r < 8; r++) {
            float pr = swzx<0x401F>(vr[r]);
            float pi = swzx<0x401F>(vi[r]);
            float tr = fmaf(g, vr[r], pr), ti = fmaf(g, vi[r], pi);
            vr[r] = tr * c - ti * s;
            vi[r] = tr * s + ti * c;
        }
    }
    // j=2, d=8: ds_swizzle xor-8
    {
        const float c = cA[2], s = sA[2], g = sg[2];
#pragma unroll
        for (int r = 0; r < 8; r++) {
            float pr = swzx<0x201F>(vr[r]);
            float pi = swzx<0x201F>(vi[r]);
            float tr = fmaf(g, vr[r], pr), ti = fmaf(g, vi[r], pi);
            vr[r] = tr * c - ti * s;
            vi[r] = tr * s + ti * c;
        }
    }
    // j=3, d=4: ds_swizzle xor-4
    {
        const float c = cA[3], s = sA[3], g = sg[3];
#pragma unroll
        for (int r = 0; r < 8; r++) {
            float pr = swzx<0x101F>(vr[r]);
            float pi = swzx<0x101F>(vi[r]);
            float tr = fmaf(g, vr[r], pr), ti = fmaf(g, vi[r], pi);
            vr[r] = tr * c - ti * s;
            vi[r] = tr * s + ti * c;
        }
    }
    // j=4, d=2: DPP quad_perm xor-2 (VALU)
    {
        const float c = cA[4], s = sA[4], g = sg[4];
#pragma unroll
        for (int r = 0; r < 8; r++) {
            float pr = xdpp<0x4E>(vr[r]);
            float pi = xdpp<0x4E>(vi[r]);
            float tr = fmaf(g, vr[r], pr), ti = fmaf(g, vi[r], pi);
            vr[r] = tr * c - ti * s;
            vi[r] = tr * s + ti * c;
        }
    }
    // j=5, d=1: DPP quad_perm xor-1 (VALU)
    {
        const float c = cA[5], s = sA[5], g = sg[5];
#pragma unroll
        for (int r = 0; r < 8; r++) {
            float pr = xdpp<0xB1>(vr[r]);
            float pi = xdpp<0xB1>(vi[r]);
            float tr = fmaf(g, vr[r], pr), ti = fmaf(g, vi[r], pi);
            vr[r] = tr * c - ti * s;
            vi[r] = tr * s + ti * c;
        }
    }
    // W512^{n2*k1} twiddle
#pragma unroll
    for (int r = 1; r < 8; r++) {
        float tr = vr[r], ti = vi[r];
        vr[r] = tr * br[r] - ti * bi[r];
        vi[r] = tr * bi[r] + ti * br[r];
    }
    // in-register 8-pt DIF over n2
    const float RH = 0.70710678118654752f;
    {
        float t0r=vr[0]+vr[4], t0i=vi[0]+vi[4];
        float d0r=vr[0]-vr[4], d0i=vi[0]-vi[4];
        float t1r=vr[1]+vr[5], t1i=vi[1]+vi[5];
        float d1r=vr[1]-vr[5], d1i=vi[1]-vi[5];
        float t2r=vr[2]+vr[6], t2i=vi[2]+vi[6];
        float d2r=vr[2]-vr[6], d2i=vi[2]-vi[6];
        float t3r=vr[3]+vr[7], t3i=vi[3]+vi[7];
        float d3r=vr[3]-vr[7], d3i=vi[3]-vi[7];
        vr[0]=t0r; vi[0]=t0i; vr[1]=t1r; vi[1]=t1i;
        vr[2]=t2r; vi[2]=t2i; vr[3]=t3r; vi[3]=t3i;
        vr[4]=d0r;                 vi[4]=d0i;
        vr[5]=(d1r+d1i)*RH;        vi[5]=(d1i-d1r)*RH;
        vr[6]=d2i;                 vi[6]=-d2r;
        vr[7]=(d3i-d3r)*RH;        vi[7]=-(d3r+d3i)*RH;
    }
    {
        float t0r=vr[0]+vr[2], t0i=vi[0]+vi[2];
        float d0r=vr[0]-vr[2], d0i=vi[0]-vi[2];
        float t1r=vr[1]+vr[3], t1i=vi[1]+vi[3];
        float d1r=vr[1]-vr[3], d1i=vi[1]-vi[3];
        vr[0]=t0r; vi[0]=t0i; vr[1]=t1r; vi[1]=t1i;
        vr[2]=d0r; vi[2]=d0i; vr[3]=d1i; vi[3]=-d1r;
        float t4r=vr[4]+vr[6], t4i=vi[4]+vi[6];
        float d4r=vr[4]-vr[6], d4i=vi[4]-vi[6];
        float t5r=vr[5]+vr[7], t5i=vi[5]+vi[7];
        float d5r=vr[5]-vr[7], d5i=vi[5]-vi[7];
        vr[4]=t4r; vi[4]=t4i; vr[5]=t5r; vi[5]=t5i;
        vr[6]=d4r; vi[6]=d4i; vr[7]=d5i; vi[7]=-d5r;
    }
    {
        float t0r=vr[0]+vr[1], t0i=vi[0]+vi[1];
        float d0r=vr[0]-vr[1], d0i=vi[0]-vi[1];
        vr[0]=t0r; vi[0]=t0i; vr[1]=d0r; vi[1]=d0i;
        float t2r=vr[2]+vr[3], t2i=vi[2]+vi[3];
        float d2r=vr[2]-vr[3], d2i=vi[2]-vi[3];
        vr[2]=t2r; vi[2]=t2i; vr[3]=d2r; vi[3]=d2i;
        float t4r=vr[4]+vr[5], t4i=vi[4]+vi[5];
        float d4r=vr[4]-vr[5], d4i=vi[4]-vi[5];
        vr[4]=t4r; vi[4]=t4i; vr[5]=d4r; vi[5]=d4i;
        float t6r=vr[6]+vr[7], t6i=vi[6]+vi[7];
        float d6r=vr[6]-vr[7], d6i=vi[6]-vi[7];
        vr[6]=t6r; vi[6]=t6i; vr[7]=d6r; vi[7]=d6i;
    }
}

__global__ __launch_bounds__(256) void fbank_kernel(const float* __restrict__ x,
                                                    const float* __restrict__ filters,
                                                    float* __restrict__ out,
                                                    unsigned* __restrict__ ticket,
                                                    int num_frames) {
    __shared__ int   lo_lds[NFILT];
    __shared__ float pw[WAVES][2][PWPAD];   // planar: [wave][frame a/b][bin]

    const int t = threadIdx.x;
    const int l = t & 63;
    const int w = t >> 6;
    float* pa_pl = pw[w][0];
    float* pb_pl = pw[w][1];

    // zero this wave's pad bins once (never rewritten)
    if (l < PWPAD - 257) { pa_pl[257 + l] = 0.0f; pb_pl[257 + l] = 0.0f; }

    // ---- wave 0: batched filter-window scan (verified in R4) ----
    if (w == 0) {
        int lo = 257;
#pragma unroll 4
        for (int k0 = 0; k0 < 264; k0 += 8) {
            float fv[8];
#pragma unroll
            for (int i = 0; i < 8; i++) {
                int k = k0 + i;
                fv[i] = (k < 257) ? filters[k * NFILT + l] : 0.0f;
            }
#pragma unroll
            for (int i = 0; i < 8; i++) {
                if (fv[i] != 0.0f && lo == 257) lo = k0 + i;
            }
        }
        if (lo > 256) lo = 256;
        lo_lds[l] = lo & ~3;        // float4-aligned window start
    }

    // ---- loop-invariant twiddles (registers) ----
    const int rl = (int)(__brev((unsigned)l) >> 26);    // rev6(lane) = k1
    float cA[6], sA[6], sg[6];
#pragma unroll
    for (int j = 0; j < 6; j++) {
        const int d = 32 >> j;
        const int hi = l & d;
        float th = -2.0f * (float)M_PI * (float)(l & (d - 1)) / (float)(2 * d);
        cA[j] = hi ? cosf(th) : 1.0f;
        sA[j] = hi ? sinf(th) : 0.0f;
        sg[j] = hi ? -1.0f : 1.0f;
    }
    float br[8], bi[8];
    {
        float th = -2.0f * (float)M_PI * (float)rl * (1.0f / 512.0f);
        float c1 = cosf(th), s1 = sinf(th);
        br[0] = 1.0f; bi[0] = 0.0f; br[1] = c1; bi[1] = s1;
#pragma unroll
        for (int r = 2; r < 8; r++) {
            float pr_ = br[r - 1], pi_ = bi[r - 1];
            br[r] = pr_ * c1 - pi_ * s1;
            bi[r] = pr_ * s1 + pi_ * c1;
        }
    }
    const int Lp = (int)(__brev((unsigned)((64 - rl) & 63)) >> 26);  // conj partner lane

    __syncthreads();
    const int lo4 = lo_lds[l];

    // ---- per-lane mel weights in registers (filters outside window are 0) ----
    float4 w4[NQ];
#pragma unroll
    for (int q = 0; q < NQ; q++) {
        int k0 = lo4 + 4 * q;
        w4[q].x = (k0 + 0 <= 256) ? filters[(k0 + 0) * NFILT + l] : 0.0f;
        w4[q].y = (k0 + 1 <= 256) ? filters[(k0 + 1) * NFILT + l] : 0.0f;
        w4[q].z = (k0 + 2 <= 256) ? filters[(k0 + 2) * NFILT + l] : 0.0f;
        w4[q].w = (k0 + 3 <= 256) ? filters[(k0 + 3) * NFILT + l] : 0.0f;
    }

    const int npairs = (num_frames + 1) >> 1;

    // ---- atomic-ticket work loop; next ticket prefetched under current pair ----
    int cur = 0;
    if (l == 0) cur = (int)atomicAdd(ticket, 1u);
    cur = __builtin_amdgcn_readfirstlane(cur);

    while (cur < npairs) {
        int nxt = 0;
        if (l == 0) nxt = (int)atomicAdd(ticket, 1u);   // latency hidden by compute
        nxt = __builtin_amdgcn_readfirstlane(nxt);

        const long fa = 2L * cur;
        const bool hasb = (fa + 1) < num_frames;
        const long ba = fa * FRAME_STEP;

        float vr[8], vi[8];
        load_pre(x, ba, l, true, vr);
        load_pre(x, ba + FRAME_STEP, l, hasb, vi);

        fft512(vr, vi, cA, sA, sg, br, bi);
        // reg p holds Z[rev6(l) + 64*rev3(p)]; needed: k2=0..3 in p={0,4,2,6},
        // plus bin 256 = lane 0's p=1.

        // ---- conj-symmetry untangle: Zc[k]=conj(Z[512-k]); partner of (rl,k2)
        //      is (lane Lp, reg 7-p); lane 0 pairs with itself ----
        float c0r = __shfl(vr[7], Lp, 64), c0i = __shfl(vi[7], Lp, 64);  // p=0
        float c1r = __shfl(vr[3], Lp, 64), c1i = __shfl(vi[3], Lp, 64);  // p=4
        float c2r = __shfl(vr[5], Lp, 64), c2i = __shfl(vi[5], Lp, 64);  // p=2
        float c3r = __shfl(vr[1], Lp, 64), c3i = __shfl(vi[1], Lp, 64);  // p=6
        if (l == 0) {
            c0r = vr[0]; c0i = vi[0];
            c1r = vr[7]; c1i = vi[7];
            c2r = vr[3]; c2i = vi[3];
            c3r = vr[5]; c3i = vi[5];
        }
        const float S4 = (1.0f / 512.0f) * 0.25f;
        {   // bins rl + {0,64,128,192}: planar b32 writes, 2 lanes/bank = free
            float zr = vr[0], zi = vi[0];
            float e1 = zr + c0r, e2 = zi - c0i, o1 = zi + c0i, o2 = c0r - zr;
            pa_pl[rl] = (e1*e1 + e2*e2) * S4;
            pb_pl[rl] = (o1*o1 + o2*o2) * S4;
        }
        {
            float zr = vr[4], zi = vi[4];
            float e1 = zr + c1r, e2 = zi - c1i, o1 = zi + c1i, o2 = c1r - zr;
            pa_pl[rl + 64] = (e1*e1 + e2*e2) * S4;
            pb_pl[rl + 64] = (o1*o1 + o2*o2) * S4;
        }
        {
            float zr = vr[2], zi = vi[2];
            float e1 = zr + c2r, e2 = zi - c2i, o1 = zi + c2i, o2 = c2r - zr;
            pa_pl[rl + 128] = (e1*e1 + e2*e2) * S4;
            pb_pl[rl + 128] = (o1*o1 + o2*o2) * S4;
        }
        {
            float zr = vr[6], zi = vi[6];
            float e1 = zr + c3r, e2 = zi - c3i, o1 = zi + c3i, o2 = c3r - zr;
            pa_pl[rl + 192] = (e1*e1 + e2*e2) * S4;
            pb_pl[rl + 192] = (o1*o1 + o2*o2) * S4;
        }
        if (l == 0) {
            pa_pl[256] = vr[1] * vr[1] * (1.0f / 512.0f);
            pb_pl[256] = vi[1] * vi[1] * (1.0f / 512.0f);
        }

        asm volatile("s_waitcnt lgkmcnt(0)" ::: "memory");  // wave-local LDS fence

        // ---- sparse mel matmul: aligned float4 reads, weights in VGPRs ----
        float ac0 = 1e-30f, ac1 = 1e-30f;
#pragma unroll
        for (int q = 0; q < NQ; q++) {
            const float4 pa = *reinterpret_cast<const float4*>(&pa_pl[lo4 + 4 * q]);
            const float4 pb = *reinterpret_cast<const float4*>(&pb_pl[lo4 + 4 * q]);
            ac0 = fmaf(w4[q].x, pa.x, ac0);
            ac0 = fmaf(w4[q].y, pa.y, ac0);
            ac0 = fmaf(w4[q].z, pa.z, ac0);
            ac0 = fmaf(w4[q].w, pa.w, ac0);
            ac1 = fmaf(w4[q].x, pb.x, ac1);
            ac1 = fmaf(w4[q].y, pb.y, ac1);
            ac1 = fmaf(w4[q].z, pb.z, ac1);
            ac1 = fmaf(w4[q].w, pb.w, ac1);
        }

        // ---- per-frame normalize: DPP/swizzle reductions ----
        float sa = ac0, sb = ac1;
        sum64x2(sa, sb);
        const float ma = sa * (1.0f / 64.0f), mb = sb * (1.0f / 64.0f);
        const float da = ac0 - ma, db = ac1 - mb;
        float qa = da * da, qb = db * db;
        sum64x2(qa, qb);

        out[fa * NFILT + l] = da * rsqrtf(qa * (1.0f / 64.0f));
        if (hasb)
            out[(fa + 1) * NFILT + l] = db * rsqrtf(qb * (1.0f / 64.0f));

        cur = nxt;
    }
}

extern "C" void kernel_launch(void* const* d_in, const int* in_sizes, int n_in,
                              void* d_out, int out_size, void* d_ws, size_t ws_size,
                              hipStream_t stream) {
    (void)ws_size; (void)n_in; (void)in_sizes;
    const float* x = (const float*)d_in[0];
    const float* filters = (const float*)d_in[1];
    float* out = (float*)d_out;
    unsigned* ticket = (unsigned*)d_ws;
    const int num_frames = out_size / NFILT;
    hipMemsetAsync(ticket, 0, sizeof(unsigned), stream);
    fbank_kernel<<<NBLOCKS, 256, 0, stream>>>(x, filters, out, ticket, num_frames);
}

// Round 7
// 147.894 us; speedup vs baseline: 3.0567x; 3.0567x over previous
//
#include <hip/hip_runtime.h>
#include <math.h>

#define NFILT 64
#define FRAME_STEP 160
#define NQ 7               // 7 float4 = 28 weight slots/lane (window<=24 + align<=3)
#define WAVES 4
#define NBLOCKS 1563       // 6252 waves: 25000 pairs -> 4 per wave (+-1)
#define PWPAD 284          // 257 bins + 27 pad so the aligned float4 window can overrun

// ---------------- cross-lane primitives (verified passing in R6) ----------------
template<int CTRL>
__device__ __forceinline__ float xdpp(float v) {   // DPP lane shuffle (VALU pipe)
    return __int_as_float(__builtin_amdgcn_update_dpp(
        0, __float_as_int(v), CTRL, 0xF, 0xF, true));
}
template<int OFF>
__device__ __forceinline__ float swzx(float v) {   // ds_swizzle BitMode (1 DS op)
    return __int_as_float(__builtin_amdgcn_ds_swizzle(__float_as_int(v), OFF));
}
// full-wave sum broadcast to all lanes, two independent chains interleaved
__device__ __forceinline__ void sum64x2(float &u, float &w) {
    u += xdpp<0xB1>(u);   w += xdpp<0xB1>(w);    // quad_perm xor 1
    u += xdpp<0x4E>(u);   w += xdpp<0x4E>(w);    // quad_perm xor 2
    u += xdpp<0x124>(u);  w += xdpp<0x124>(w);   // row_ror:4
    u += xdpp<0x128>(u);  w += xdpp<0x128>(w);   // row_ror:8  -> row(16) sums
    u += swzx<0x401F>(u); w += swzx<0x401F>(w);  // xor 16     -> 32-half sums
    u += __shfl_xor(u, 32, 64);
    w += __shfl_xor(w, 32, 64);                  // cross-half -> full-wave total
}

// ---- load one 400-sample frame (8/lane, lanes 0..49) + pre-emphasis ----
__device__ __forceinline__ void load_pre(const float* __restrict__ x, long base,
                                         int l, bool valid, float (&v)[8]) {
    float a0=0,a1=0,a2=0,a3=0,a4=0,a5=0,a6=0,a7=0;
    if (valid && l < 50) {
        const float4* p4 = reinterpret_cast<const float4*>(x + base + 8 * l);
        float4 A = p4[0], B = p4[1];
        a0=A.x; a1=A.y; a2=A.z; a3=A.w; a4=B.x; a5=B.y; a6=B.z; a7=B.w;
    }
    float edge = 0.0f;
    if (valid && base > 0) edge = x[base - 1];   // pre[0] of audio = x[0] - 0.97*0
    float prev = __shfl_up(a7, 1, 64);
    if (l == 0) prev = edge;
    const bool act = valid && (l < 50);
    v[0] = act ? fmaf(-0.97f, prev, a0) : 0.0f;
    v[1] = act ? fmaf(-0.97f, a0, a1) : 0.0f;
    v[2] = act ? fmaf(-0.97f, a1, a2) : 0.0f;
    v[3] = act ? fmaf(-0.97f, a2, a3) : 0.0f;
    v[4] = act ? fmaf(-0.97f, a3, a4) : 0.0f;
    v[5] = act ? fmaf(-0.97f, a4, a5) : 0.0f;
    v[6] = act ? fmaf(-0.97f, a5, a6) : 0.0f;
    v[7] = act ? fmaf(-0.97f, a6, a7) : 0.0f;
}

// ---- 512-pt FFT (verified R6): 64-pt cross-lane + W512 twiddle + radix-8 ----
__device__ __forceinline__ void fft512(float (&vr)[8], float (&vi)[8],
                                       const float (&cA)[6], const float (&sA)[6],
                                       const float (&sg)[6],
                                       const float (&br)[8], const float (&bi)[8]) {
    {   // j=0, d=32
        const float c = cA[0], s = sA[0], g = sg[0];
#pragma unroll
        for (int r = 0; r < 8; r++) {
            float pr = __shfl_xor(vr[r], 32, 64);
            float pi = __shfl_xor(vi[r], 32, 64);
            float tr = fmaf(g, vr[r], pr), ti = fmaf(g, vi[r], pi);
            vr[r] = tr * c - ti * s;
            vi[r] = tr * s + ti * c;
        }
    }
    {   // j=1, d=16: ds_swizzle xor-16
        const float c = cA[1], s = sA[1], g = sg[1];
#pragma unroll
        for (int r = 0; r < 8; r++) {
            float pr = swzx<0x401F>(vr[r]);
            float pi = swzx<0x401F>(vi[r]);
            float tr = fmaf(g, vr[r], pr), ti = fmaf(g, vi[r], pi);
            vr[r] = tr * c - ti * s;
            vi[r] = tr * s + ti * c;
        }
    }
    {   // j=2, d=8: ds_swizzle xor-8
        const float c = cA[2], s = sA[2], g = sg[2];
#pragma unroll
        for (int r = 0; r < 8; r++) {
            float pr = swzx<0x201F>(vr[r]);
            float pi = swzx<0x201F>(vi[r]);
            float tr = fmaf(g, vr[r], pr), ti = fmaf(g, vi[r], pi);
            vr[r] = tr * c - ti * s;
            vi[r] = tr * s + ti * c;
        }
    }
    {   // j=3, d=4: ds_swizzle xor-4
        const float c = cA[3], s = sA[3], g = sg[3];
#pragma unroll
        for (int r = 0; r < 8; r++) {
            float pr = swzx<0x101F>(vr[r]);
            float pi = swzx<0x101F>(vi[r]);
            float tr = fmaf(g, vr[r], pr), ti = fmaf(g, vi[r], pi);
            vr[r] = tr * c - ti * s;
            vi[r] = tr * s + ti * c;
        }
    }
    {   // j=4, d=2: DPP quad_perm xor-2
        const float c = cA[4], s = sA[4], g = sg[4];
#pragma unroll
        for (int r = 0; r < 8; r++) {
            float pr = xdpp<0x4E>(vr[r]);
            float pi = xdpp<0x4E>(vi[r]);
            float tr = fmaf(g, vr[r], pr), ti = fmaf(g, vi[r], pi);
            vr[r] = tr * c - ti * s;
            vi[r] = tr * s + ti * c;
        }
    }
    {   // j=5, d=1: DPP quad_perm xor-1
        const float c = cA[5], s = sA[5], g = sg[5];
#pragma unroll
        for (int r = 0; r < 8; r++) {
            float pr = xdpp<0xB1>(vr[r]);
            float pi = xdpp<0xB1>(vi[r]);
            float tr = fmaf(g, vr[r], pr), ti = fmaf(g, vi[r], pi);
            vr[r] = tr * c - ti * s;
            vi[r] = tr * s + ti * c;
        }
    }
#pragma unroll
    for (int r = 1; r < 8; r++) {
        float tr = vr[r], ti = vi[r];
        vr[r] = tr * br[r] - ti * bi[r];
        vi[r] = tr * bi[r] + ti * br[r];
    }
    const float RH = 0.70710678118654752f;
    {
        float t0r=vr[0]+vr[4], t0i=vi[0]+vi[4];
        float d0r=vr[0]-vr[4], d0i=vi[0]-vi[4];
        float t1r=vr[1]+vr[5], t1i=vi[1]+vi[5];
        float d1r=vr[1]-vr[5], d1i=vi[1]-vi[5];
        float t2r=vr[2]+vr[6], t2i=vi[2]+vi[6];
        float d2r=vr[2]-vr[6], d2i=vi[2]-vi[6];
        float t3r=vr[3]+vr[7], t3i=vi[3]+vi[7];
        float d3r=vr[3]-vr[7], d3i=vi[3]-vi[7];
        vr[0]=t0r; vi[0]=t0i; vr[1]=t1r; vi[1]=t1i;
        vr[2]=t2r; vi[2]=t2i; vr[3]=t3r; vi[3]=t3i;
        vr[4]=d0r;                 vi[4]=d0i;
        vr[5]=(d1r+d1i)*RH;        vi[5]=(d1i-d1r)*RH;
        vr[6]=d2i;                 vi[6]=-d2r;
        vr[7]=(d3i-d3r)*RH;        vi[7]=-(d3r+d3i)*RH;
    }
    {
        float t0r=vr[0]+vr[2], t0i=vi[0]+vi[2];
        float d0r=vr[0]-vr[2], d0i=vi[0]-vi[2];
        float t1r=vr[1]+vr[3], t1i=vi[1]+vi[3];
        float d1r=vr[1]-vr[3], d1i=vi[1]-vi[3];
        vr[0]=t0r; vi[0]=t0i; vr[1]=t1r; vi[1]=t1i;
        vr[2]=d0r; vi[2]=d0i; vr[3]=d1i; vi[3]=-d1r;
        float t4r=vr[4]+vr[6], t4i=vi[4]+vi[6];
        float d4r=vr[4]-vr[6], d4i=vi[4]-vi[6];
        float t5r=vr[5]+vr[7], t5i=vi[5]+vi[7];
        float d5r=vr[5]-vr[7], d5i=vi[5]-vi[7];
        vr[4]=t4r; vi[4]=t4i; vr[5]=t5r; vi[5]=t5i;
        vr[6]=d4r; vi[6]=d4i; vr[7]=d5i; vi[7]=-d5r;
    }
    {
        float t0r=vr[0]+vr[1], t0i=vi[0]+vi[1];
        float d0r=vr[0]-vr[1], d0i=vi[0]-vi[1];
        vr[0]=t0r; vi[0]=t0i; vr[1]=d0r; vi[1]=d0i;
        float t2r=vr[2]+vr[3], t2i=vi[2]+vi[3];
        float d2r=vr[2]-vr[3], d2i=vi[2]-vi[3];
        vr[2]=t2r; vi[2]=t2i; vr[3]=d2r; vi[3]=d2i;
        float t4r=vr[4]+vr[5], t4i=vi[4]+vi[5];
        float d4r=vr[4]-vr[5], d4i=vi[4]-vi[5];
        vr[4]=t4r; vi[4]=t4i; vr[5]=d4r; vi[5]=d4i;
        float t6r=vr[6]+vr[7], t6i=vi[6]+vi[7];
        float d6r=vr[6]-vr[7], d6i=vi[6]-vi[7];
        vr[6]=t6r; vi[6]=t6i; vr[7]=d6r; vi[7]=d6i;
    }
}

__global__ __launch_bounds__(256) void fbank_kernel(const float* __restrict__ x,
                                                    const float* __restrict__ filters,
                                                    float* __restrict__ out,
                                                    int num_frames) {
    __shared__ int   lo_lds[NFILT];
    __shared__ float pw[WAVES][2][PWPAD];   // planar: [wave][frame a/b][bin]

    const int t = threadIdx.x;
    const int l = t & 63;
    const int w = t >> 6;
    float* pa_pl = pw[w][0];
    float* pb_pl = pw[w][1];

    // zero this wave's pad bins once (never rewritten)
    if (l < PWPAD - 257) { pa_pl[257 + l] = 0.0f; pb_pl[257 + l] = 0.0f; }

    // ---- wave 0: batched filter-window scan (verified R4/R6) ----
    if (w == 0) {
        int lo = 257;
#pragma unroll 4
        for (int k0 = 0; k0 < 264; k0 += 8) {
            float fv[8];
#pragma unroll
            for (int i = 0; i < 8; i++) {
                int k = k0 + i;
                fv[i] = (k < 257) ? filters[k * NFILT + l] : 0.0f;
            }
#pragma unroll
            for (int i = 0; i < 8; i++) {
                if (fv[i] != 0.0f && lo == 257) lo = k0 + i;
            }
        }
        if (lo > 256) lo = 256;
        lo_lds[l] = lo & ~3;        // float4-aligned window start
    }

    // ---- loop-invariant twiddles (registers) ----
    const int rl = (int)(__brev((unsigned)l) >> 26);    // rev6(lane) = k1
    float cA[6], sA[6], sg[6];
#pragma unroll
    for (int j = 0; j < 6; j++) {
        const int d = 32 >> j;
        const int hi = l & d;
        float th = -2.0f * (float)M_PI * (float)(l & (d - 1)) / (float)(2 * d);
        cA[j] = hi ? cosf(th) : 1.0f;
        sA[j] = hi ? sinf(th) : 0.0f;
        sg[j] = hi ? -1.0f : 1.0f;
    }
    float br[8], bi[8];
    {
        float th = -2.0f * (float)M_PI * (float)rl * (1.0f / 512.0f);
        float c1 = cosf(th), s1 = sinf(th);
        br[0] = 1.0f; bi[0] = 0.0f; br[1] = c1; bi[1] = s1;
#pragma unroll
        for (int r = 2; r < 8; r++) {
            float pr_ = br[r - 1], pi_ = bi[r - 1];
            br[r] = pr_ * c1 - pi_ * s1;
            bi[r] = pr_ * s1 + pi_ * c1;
        }
    }
    const int Lp = (int)(__brev((unsigned)((64 - rl) & 63)) >> 26);  // conj partner lane

    __syncthreads();
    const int lo4 = lo_lds[l];

    // ---- per-lane mel weights in registers (filters outside window are 0) ----
    float4 w4[NQ];
#pragma unroll
    for (int q = 0; q < NQ; q++) {
        int k0 = lo4 + 4 * q;
        w4[q].x = (k0 + 0 <= 256) ? filters[(k0 + 0) * NFILT + l] : 0.0f;
        w4[q].y = (k0 + 1 <= 256) ? filters[(k0 + 1) * NFILT + l] : 0.0f;
        w4[q].z = (k0 + 2 <= 256) ? filters[(k0 + 2) * NFILT + l] : 0.0f;
        w4[q].w = (k0 + 3 <= 256) ? filters[(k0 + 3) * NFILT + l] : 0.0f;
    }

    const int gw = blockIdx.x * WAVES + w;
    const int totw = NBLOCKS * WAVES;          // 6252
    const int npairs = (num_frames + 1) >> 1;

    // ---- static grid-stride over pairs (no atomics) ----
    for (int pair = gw; pair < npairs; pair += totw) {
        const long fa = 2L * pair;
        const bool hasb = (fa + 1) < num_frames;
        const long ba = fa * FRAME_STEP;

        float vr[8], vi[8];
        load_pre(x, ba, l, true, vr);
        load_pre(x, ba + FRAME_STEP, l, hasb, vi);

        fft512(vr, vi, cA, sA, sg, br, bi);
        // reg p holds Z[rev6(l) + 64*rev3(p)]; needed: k2=0..3 in p={0,4,2,6},
        // plus bin 256 = lane 0's p=1.

        // ---- conj-symmetry untangle ----
        float c0r = __shfl(vr[7], Lp, 64), c0i = __shfl(vi[7], Lp, 64);  // p=0
        float c1r = __shfl(vr[3], Lp, 64), c1i = __shfl(vi[3], Lp, 64);  // p=4
        float c2r = __shfl(vr[5], Lp, 64), c2i = __shfl(vi[5], Lp, 64);  // p=2
        float c3r = __shfl(vr[1], Lp, 64), c3i = __shfl(vi[1], Lp, 64);  // p=6
        if (l == 0) {
            c0r = vr[0]; c0i = vi[0];
            c1r = vr[7]; c1i = vi[7];
            c2r = vr[3]; c2i = vi[3];
            c3r = vr[5]; c3i = vi[5];
        }
        const float S4 = (1.0f / 512.0f) * 0.25f;
        {   // bins rl + {0,64,128,192}: planar b32 writes, 2 lanes/bank = free
            float zr = vr[0], zi = vi[0];
            float e1 = zr + c0r, e2 = zi - c0i, o1 = zi + c0i, o2 = c0r - zr;
            pa_pl[rl] = (e1*e1 + e2*e2) * S4;
            pb_pl[rl] = (o1*o1 + o2*o2) * S4;
        }
        {
            float zr = vr[4], zi = vi[4];
            float e1 = zr + c1r, e2 = zi - c1i, o1 = zi + c1i, o2 = c1r - zr;
            pa_pl[rl + 64] = (e1*e1 + e2*e2) * S4;
            pb_pl[rl + 64] = (o1*o1 + o2*o2) * S4;
        }
        {
            float zr = vr[2], zi = vi[2];
            float e1 = zr + c2r, e2 = zi - c2i, o1 = zi + c2i, o2 = c2r - zr;
            pa_pl[rl + 128] = (e1*e1 + e2*e2) * S4;
            pb_pl[rl + 128] = (o1*o1 + o2*o2) * S4;
        }
        {
            float zr = vr[6], zi = vi[6];
            float e1 = zr + c3r, e2 = zi - c3i, o1 = zi + c3i, o2 = c3r - zr;
            pa_pl[rl + 192] = (e1*e1 + e2*e2) * S4;
            pb_pl[rl + 192] = (o1*o1 + o2*o2) * S4;
        }
        if (l == 0) {
            pa_pl[256] = vr[1] * vr[1] * (1.0f / 512.0f);
            pb_pl[256] = vi[1] * vi[1] * (1.0f / 512.0f);
        }

        asm volatile("s_waitcnt lgkmcnt(0)" ::: "memory");  // wave-local LDS fence

        // ---- sparse mel matmul: aligned float4 reads, weights in VGPRs ----
        float ac0 = 1e-30f, ac1 = 1e-30f;
#pragma unroll
        for (int q = 0; q < NQ; q++) {
            const float4 pa = *reinterpret_cast<const float4*>(&pa_pl[lo4 + 4 * q]);
            const float4 pb = *reinterpret_cast<const float4*>(&pb_pl[lo4 + 4 * q]);
            ac0 = fmaf(w4[q].x, pa.x, ac0);
            ac0 = fmaf(w4[q].y, pa.y, ac0);
            ac0 = fmaf(w4[q].z, pa.z, ac0);
            ac0 = fmaf(w4[q].w, pa.w, ac0);
            ac1 = fmaf(w4[q].x, pb.x, ac1);
            ac1 = fmaf(w4[q].y, pb.y, ac1);
            ac1 = fmaf(w4[q].z, pb.z, ac1);
            ac1 = fmaf(w4[q].w, pb.w, ac1);
        }

        // ---- per-frame normalize: DPP/swizzle reductions ----
        float sa = ac0, sb = ac1;
        sum64x2(sa, sb);
        const float ma = sa * (1.0f / 64.0f), mb = sb * (1.0f / 64.0f);
        const float da = ac0 - ma, db = ac1 - mb;
        float qa = da * da, qb = db * db;
        sum64x2(qa, qb);

        out[fa * NFILT + l] = da * rsqrtf(qa * (1.0f / 64.0f));
        if (hasb)
            out[(fa + 1) * NFILT + l] = db * rsqrtf(qb * (1.0f / 64.0f));
    }
}

extern "C" void kernel_launch(void* const* d_in, const int* in_sizes, int n_in,
                              void* d_out, int out_size, void* d_ws, size_t ws_size,
                              hipStream_t stream) {
    (void)d_ws; (void)ws_size; (void)n_in; (void)in_sizes;
    const float* x = (const float*)d_in[0];
    const float* filters = (const float*)d_in[1];
    float* out = (float*)d_out;
    const int num_frames = out_size / NFILT;
    fbank_kernel<<<NBLOCKS, 256, 0, stream>>>(x, filters, out, num_frames);
}